// Round 15
// baseline (445.201 us; speedup 1.0000x reference)
//
#include <hip/hip_runtime.h>
#include <hip/hip_bf16.h>
#include <cstdint>
#include <cstddef>

#define B_ 4
#define T_ 2048
#define C_ 1024
#define H_ 16
#define D_ 64
#define M_ (B_*T_)   // 8192 rows

using bf16_t = __hip_bfloat16;
typedef __bf16 v8bf __attribute__((ext_vector_type(8)));
typedef float  v4f  __attribute__((ext_vector_type(4)));
typedef float  f32x16 __attribute__((ext_vector_type(16)));

// 1/sqrt(D) * log2(e): folded into Q at the QKV epilogue; softmax in exp2 domain.
#define QSCALE (0.125f * 1.44269504088896340736f)

static __device__ __forceinline__ bf16_t f2bf(float v){ return __float2bfloat16(v); }
static __device__ __forceinline__ float bfraw2f(unsigned short u){
  union { unsigned int i; float f; } c; c.i = ((unsigned int)u) << 16; return c.f;
}

// async global->LDS, 16B per lane. LDS dest is wave-uniform base + lane*16.
static __device__ __forceinline__ void glds16(const bf16_t* g, bf16_t* l){
  __builtin_amdgcn_global_load_lds((__attribute__((address_space(1))) void*)g,
                                   (__attribute__((address_space(3))) void*)l, 16, 0, 0);
}

static __device__ __forceinline__ uint32_t cvt_pk_bf16(float lo, float hi){
  uint32_t w;
  asm("v_cvt_pk_bf16_f32 %0, %1, %2" : "=v"(w) : "v"(lo), "v"(hi));
  return w;
}

// tanh-form GELU in exp2 domain (branch-free, inf-safe).
static __device__ __forceinline__ float gelu_fast(float x){
  const float u = __builtin_fmaf(0.044715f * x * x, x, x);
  const float e = __builtin_amdgcn_exp2f(2.3021256637f * u);
  return x - x * __builtin_amdgcn_rcpf(1.0f + e);
}

// ---------------- merged transpose + cast fp32[K][N] -> bf16[N][K], 4 jobs ----------------
__global__ void k_transpose_all(const float* __restrict__ in0, bf16_t* __restrict__ out0,
                                const float* __restrict__ in1, bf16_t* __restrict__ out1,
                                const float* __restrict__ in2, bf16_t* __restrict__ out2,
                                const float* __restrict__ in3, bf16_t* __restrict__ out3){
  __shared__ float tile[32][33];
  const int bid = blockIdx.x;
  const float* in; bf16_t* out; int K, N, lb;
  if (bid < 3072)      { in=in0; out=out0; K=1024; N=3072; lb=bid; }
  else if (bid < 4096) { in=in1; out=out1; K=1024; N=1024; lb=bid-3072; }
  else if (bid < 8192) { in=in2; out=out2; K=1024; N=4096; lb=bid-4096; }
  else                 { in=in3; out=out3; K=4096; N=1024; lb=bid-8192; }
  const int nbx = N >> 5;
  const int k0 = (lb / nbx) * 32, n0 = (lb % nbx) * 32;
  const int tx = threadIdx.x, ty = threadIdx.y; // 32 x 8
  #pragma unroll
  for(int j=0;j<32;j+=8) tile[ty+j][tx] = in[(size_t)(k0+ty+j)*N + n0+tx];
  __syncthreads();
  #pragma unroll
  for(int j=0;j<32;j+=8) out[(size_t)(n0+ty+j)*K + k0+tx] = f2bf(tile[tx][ty+j]);
}

// ---------------- LayerNorm fp32 row -> bf16 row ----------------
__global__ __launch_bounds__(256) void k_layernorm(const float* __restrict__ x,
                                                   const float* __restrict__ gamma,
                                                   const float* __restrict__ beta,
                                                   bf16_t* __restrict__ out){
  int row = blockIdx.x;
  int tid = threadIdx.x;
  const float4 v = reinterpret_cast<const float4*>(x + (size_t)row*C_)[tid];
  float s  = v.x+v.y+v.z+v.w;
  float ss = v.x*v.x+v.y*v.y+v.z*v.z+v.w*v.w;
  #pragma unroll
  for(int m=1;m<64;m<<=1){ s += __shfl_xor(s,m); ss += __shfl_xor(ss,m); }
  __shared__ float sbuf[4], ssbuf[4];
  int wid = tid>>6, lane = tid&63;
  if(lane==0){ sbuf[wid]=s; ssbuf[wid]=ss; }
  __syncthreads();
  s  = sbuf[0]+sbuf[1]+sbuf[2]+sbuf[3];
  ss = ssbuf[0]+ssbuf[1]+ssbuf[2]+ssbuf[3];
  float mean = s * (1.0f/C_);
  float var  = ss * (1.0f/C_) - mean*mean;
  float rstd = rsqrtf(var + 1e-3f);
  const float4 g = reinterpret_cast<const float4*>(gamma)[tid];
  const float4 b = reinterpret_cast<const float4*>(beta)[tid];
  union { ushort4 u; bf16_t h[4]; } pk;
  pk.h[0] = f2bf(g.x*(v.x-mean)*rstd + b.x);
  pk.h[1] = f2bf(g.y*(v.y-mean)*rstd + b.y);
  pk.h[2] = f2bf(g.z*(v.z-mean)*rstd + b.z);
  pk.h[3] = f2bf(g.w*(v.w-mean)*rstd + b.w);
  *reinterpret_cast<ushort4*>(out + (size_t)row*C_ + tid*4) = pk.u;
}

// ---------------- FFN2 reduction: out = out + p0 + p1 + bias ----------------
__global__ __launch_bounds__(256)
void k_add2(const bf16_t* __restrict__ p0, const bf16_t* __restrict__ p1,
            const float* __restrict__ bias, float* out){
  const int row = blockIdx.x, tid = threadIdx.x;
  float4 xr = reinterpret_cast<const float4*>(out + (size_t)row*C_)[tid];
  const ushort4 a = reinterpret_cast<const ushort4*>(p0 + (size_t)row*C_)[tid];
  const ushort4 b = reinterpret_cast<const ushort4*>(p1 + (size_t)row*C_)[tid];
  const float4 g = reinterpret_cast<const float4*>(bias)[tid];
  xr.x += bfraw2f(a.x) + bfraw2f(b.x) + g.x;
  xr.y += bfraw2f(a.y) + bfraw2f(b.y) + g.y;
  xr.z += bfraw2f(a.z) + bfraw2f(b.z) + g.z;
  xr.w += bfraw2f(a.w) + bfraw2f(b.w) + g.w;
  reinterpret_cast<float4*>(out + (size_t)row*C_)[tid] = xr;
}

// ---------------- GEMM A: 256x256, BK=64, 8 waves (2Mx4N), FAT-PHASE (2/K-tile), PERSISTENT
// Per K-tile: 2 phases x 32 MFMA/wave (all-A reads in ph a). Phase count halved vs r13;
// per-phase MFMA content doubled (128->256 MFMA/CU) to amortize the fixed barrier/wait cost.
// Stage rotation (iteration j = tiles t0,t1; prefetch t2,t3), WAR = same-phase-as-last-read
// (the pattern proven in r10-13), landing = vmcnt(6) one phase ahead of use:
//   ph1 (t0,nh0): LDA16(0)+LDB4(0,0) | stage A(t1)h1
//   ph2 (t0,nh1): LDB4(0,1)          | stage B(t2)h0,B(t2)h1,A(t2)h0 + vmcnt(6)
//   ph3 (t1,nh0): LDA16(1)+LDB4(1,0) | stage A(t2)h1
//   ph4 (t1,nh1): LDB4(1,1)          | stage B(t3)h0,B(t3)h1,A(t3)h0 + vmcnt(6)
// Outstanding-count bookkeeping (2 glds16/half-stage): carry-in 6; ph2: 6+2+6=14 ->
// drain to 6 = exactly B(t1)+A(t1) landed (read ph3/ph4); ph4 symmetric for t2.
// Last iteration: stages guarded off, ph2/ph4 use vmcnt(0).
// MODE 0: QKV split; MODE 2: bias+GELU->bf16; MODE 4: raw bf16 split-K partial.
template<int MODE>
__global__ __launch_bounds__(512, 1)
void k_gemm9(const bf16_t* __restrict__ A, const bf16_t* __restrict__ Bt,
             const float* __restrict__ bias, const float* resid,
             void* out0, void* out1, void* out2,
             int N, int ld, int klen, int gx, int tc)
{
  __shared__ __align__(16) bf16_t As[2][2][128*64];
  __shared__ __align__(16) bf16_t Bs[2][2][128*64];
  const int tid = threadIdx.x, lane = tid & 63, w = tid >> 6;
  const int wm = w >> 2, wn = w & 3;
  const int koff = blockIdx.z * klen;

  const int sswz = ((lane & 7) ^ ((lane >> 3) & 7)) * 8;
  const int srow = w * 8 + (lane >> 3);

  int row0, col0;
  const bf16_t *Agb, *Bgb;
  auto set_tile = [&](int tile){
    const int swz = (tile & 7) * (tc >> 3) + (tile >> 3);   // bijective, tc%8==0
    const int ct = swz % gx, rt = swz / gx;
    row0 = rt * 256; col0 = ct * 256;
    Agb = A  + (size_t)(row0 + srow) * ld + koff + sswz;
    Bgb = Bt + (size_t)(col0 + srow) * ld + koff + sswz;
  };

  auto stageA = [&](int tt, int hh){
    const bf16_t* src = Agb + (size_t)(hh * 128) * ld + tt * 64;
    bf16_t* dst = &As[tt & 1][hh][w * 512];
    glds16(src, dst);
    glds16(src + (size_t)64 * ld, dst + 4096);
  };
  auto stageB = [&](int tt, int hh){
    const bf16_t* src = Bgb + (size_t)(hh * 128) * ld + tt * 64;
    bf16_t* dst = &Bs[tt & 1][hh][w * 512];
    glds16(src, dst);
    glds16(src + (size_t)64 * ld, dst + 4096);
  };
  auto stage_prologue = [&](){
    stageA(0,0); stageA(0,1); stageB(0,0); stageB(0,1);
    stageB(1,0); stageB(1,1); stageA(1,0);
  };

  v8bf af[8][2], bfv[4][2];
  v4f acc[8][4];

  auto LDA16 = [&](int bb){      // 16 reads: BOTH mh halves of this wave's A panel
    const bf16_t* base = &As[bb][wm][0];
    #pragma unroll
    for (int mh = 0; mh < 2; ++mh)
      #pragma unroll
      for (int m = 0; m < 4; ++m)
        #pragma unroll
        for (int kk = 0; kk < 2; ++kk) {
          const int r  = mh*64 + m*16 + (lane & 15);
          const int sl = (kk*4 + (lane >> 4)) ^ (lane & 7);
          af[mh*4+m][kk] = *reinterpret_cast<const v8bf*>(base + r*64 + sl*8);
        }
  };
  auto LDB4 = [&](int bb, int nh){
    const bf16_t* base = &Bs[bb][wn >> 1][0];
    #pragma unroll
    for (int n = 0; n < 2; ++n)
      #pragma unroll
      for (int kk = 0; kk < 2; ++kk) {
        const int r  = (wn & 1)*64 + (nh*2+n)*16 + (lane & 15);
        const int sl = (kk*4 + (lane >> 4)) ^ (lane & 7);
        bfv[nh*2+n][kk] = *reinterpret_cast<const v8bf*>(base + r*64 + sl*8);
      }
  };

#define MFMA_Q2(nh_) \
  __builtin_amdgcn_s_setprio(1); \
  _Pragma("unroll") \
  for (int kk = 0; kk < 2; ++kk) \
    _Pragma("unroll") \
    for (int mf = 0; mf < 8; ++mf) \
      _Pragma("unroll") \
      for (int n = 0; n < 2; ++n) \
        acc[mf][(nh_)*2+n] = __builtin_amdgcn_mfma_f32_16x16x32_bf16( \
            af[mf][kk], bfv[(nh_)*2+n][kk], acc[mf][(nh_)*2+n], 0,0,0); \
  __builtin_amdgcn_s_setprio(0);

#define BAR()   __builtin_amdgcn_s_barrier()
#define LGKM0() do { asm volatile("s_waitcnt lgkmcnt(0)" ::: "memory"); \
                     __builtin_amdgcn_sched_barrier(0); } while(0)

  const int NP = (klen >> 6) >> 1;
  int tile = blockIdx.x;
  set_tile(tile);
  stage_prologue();

  for (;;) {
    asm volatile("s_waitcnt vmcnt(6)" ::: "memory");   // drain this tile's K0 A+B
    BAR();
    #pragma unroll
    for (int mf = 0; mf < 8; ++mf)
      #pragma unroll
      for (int nf = 0; nf < 4; ++nf)
        acc[mf][nf] = (v4f){0.f, 0.f, 0.f, 0.f};

    for (int j = 0; j < NP; ++j) {
      const int t2 = 2*j + 2, t3 = 2*j + 3;
      const bool more = (j + 1 < NP);
      // ---- ph1: t0, nh0 ----
      LDA16(0); LDB4(0, 0);
      stageA(2*j + 1, 1);
      BAR(); LGKM0(); MFMA_Q2(0); BAR();
      // ---- ph2: t0, nh1 ----
      LDB4(0, 1);
      if (more) { stageB(t2, 0); stageB(t2, 1); stageA(t2, 0);
                  asm volatile("s_waitcnt vmcnt(6)" ::: "memory"); }
      else      { asm volatile("s_waitcnt vmcnt(0)" ::: "memory"); }
      BAR(); LGKM0(); MFMA_Q2(1); BAR();
      // ---- ph3: t1, nh0 ----
      LDA16(1); LDB4(1, 0);
      if (more) stageA(t2, 1);
      BAR(); LGKM0(); MFMA_Q2(0); BAR();
      // ---- ph4: t1, nh1 ----
      LDB4(1, 1);
      if (more) { stageB(t3, 0); stageB(t3, 1); stageA(t3, 0);
                  asm volatile("s_waitcnt vmcnt(6)" ::: "memory"); }
      else      { asm volatile("s_waitcnt vmcnt(0)" ::: "memory"); }
      BAR(); LGKM0(); MFMA_Q2(1); BAR();
    }

    // issue next tile's prologue BEFORE the epilogue (HBM latency hides under it)
    const int erow0 = row0, ecol0 = col0;
    const int next = tile + (int)gridDim.x;
    const bool have_next = (next < tc);
    if (have_next) { set_tile(next); stage_prologue(); }

    #pragma unroll
    for (int mf = 0; mf < 8; ++mf) {
      const int rbase = erow0 + wm*128 + mf*16 + (lane>>4)*4;
      #pragma unroll
      for (int nf = 0; nf < 4; ++nf) {
        const int c = ecol0 + wn*64 + nf*16 + (lane&15);
        #pragma unroll
        for (int i = 0; i < 4; ++i) {
          const int rr = rbase + i;
          float v = acc[mf][nf][i];
          if constexpr(MODE==0){
            const int sec = c >> 10, cc = c & 1023;
            const int h = cc >> 6, d = cc & 63;
            const int b = rr >> 11, t = rr & 2047;
            if(sec==0)      ((bf16_t*)out0)[((size_t)(b*H_ + h)*T_ + t)*D_ + d] = f2bf(v * QSCALE);
            else if(sec==1) ((bf16_t*)out1)[((size_t)(b*H_ + h)*T_ + t)*D_ + d] = f2bf(v);
            else            ((bf16_t*)out2)[((size_t)(b*H_ + h)*D_ + d)*T_ + t] = f2bf(v);
          } else if constexpr(MODE==2){
            ((bf16_t*)out0)[(size_t)rr*N + c] = f2bf(gelu_fast(v + bias[c]));
          } else {  // MODE 4: raw bf16 partial
            bf16_t* dst = blockIdx.z ? (bf16_t*)out1 : (bf16_t*)out0;
            dst[(size_t)rr*N + c] = f2bf(v);
          }
        }
      }
    }
    if (!have_next) break;
    tile = next;
  }
#undef MFMA_Q2
#undef BAR
#undef LGKM0
}

// ---------------- GEMM B: 256x128 tile, BK=64, 8 waves, 4-phase (proj only) ----
__global__ __launch_bounds__(512, 1)
void k_gemm8(const bf16_t* __restrict__ A, const bf16_t* __restrict__ Bt,
             const float* __restrict__ bias, const float* resid,
             float* out0, int N, int K, int gx)
{
  __shared__ __align__(16) bf16_t As[2][256*64];
  __shared__ __align__(16) bf16_t Bs[3][128*64];
  const int tid = threadIdx.x, lane = tid & 63, w = tid >> 6;
  const int wm = w >> 1, wn = w & 1;

  const int nwg = gx * 32;
  const int orig = blockIdx.y * gx + blockIdx.x;
  const int swz = (orig & 7) * (nwg >> 3) + (orig >> 3);
  const int ct = swz % gx, rt = swz / gx;
  const int row0 = rt * 256, col0 = ct * 128;

  const int sswz = ((lane & 7) ^ ((lane >> 3) & 7)) * 8;
  const int srow = w * 8 + (lane >> 3);
  const bf16_t* Agb = A  + (size_t)(row0 + srow) * K + sswz;
  const bf16_t* Bgb = Bt + (size_t)(col0 + srow) * K + sswz;

  auto stageA = [&](int tt){
    const bf16_t* src = Agb + tt * 64;
    bf16_t* dst = &As[tt & 1][w * 512];
    #pragma unroll
    for (int i = 0; i < 4; ++i)
      glds16(src + (size_t)(i*64) * K, dst + i*4096);
  };
  auto stageB = [&](int tt){
    const bf16_t* src = Bgb + tt * 64;
    bf16_t* dst = &Bs[tt % 3][w * 512];
    #pragma unroll
    for (int i = 0; i < 2; ++i)
      glds16(src + (size_t)(i*64) * K, dst + i*4096);
  };

  v8bf af[4][2], bfv[4][2];
  v4f acc[4][4] = {};

  auto LDA = [&](int ab){
    const bf16_t* base = &As[ab][0];
    #pragma unroll
    for (int m = 0; m < 4; ++m)
      #pragma unroll
      for (int kk = 0; kk < 2; ++kk) {
        const int r  = wm*64 + m*16 + (lane & 15);
        const int sl = (kk*4 + (lane >> 4)) ^ (lane & 7);
        af[m][kk] = *reinterpret_cast<const v8bf*>(base + r*64 + sl*8);
      }
  };
  auto LDB = [&](int bb, int nh){
    const bf16_t* base = &Bs[bb][0];
    #pragma unroll
    for (int n = 0; n < 2; ++n)
      #pragma unroll
      for (int kk = 0; kk < 2; ++kk) {
        const int r  = wn*64 + (nh*2+n)*16 + (lane & 15);
        const int sl = (kk*4 + (lane >> 4)) ^ (lane & 7);
        bfv[nh*2+n][kk] = *reinterpret_cast<const v8bf*>(base + r*64 + sl*8);
      }
  };

#define MFMA_Q(nh_) \
  __builtin_amdgcn_s_setprio(1); \
  _Pragma("unroll") \
  for (int kk = 0; kk < 2; ++kk) \
    _Pragma("unroll") \
    for (int m = 0; m < 4; ++m) \
      _Pragma("unroll") \
      for (int n = 0; n < 2; ++n) \
        acc[m][(nh_)*2+n] = __builtin_amdgcn_mfma_f32_16x16x32_bf16( \
            af[m][kk], bfv[(nh_)*2+n][kk], acc[m][(nh_)*2+n], 0,0,0); \
  __builtin_amdgcn_s_setprio(0);

#define BAR()   __builtin_amdgcn_s_barrier()
#define LGKM0() do { asm volatile("s_waitcnt lgkmcnt(0)" ::: "memory"); \
                     __builtin_amdgcn_sched_barrier(0); } while(0)
#define VM6()   asm volatile("s_waitcnt vmcnt(6)" ::: "memory")
#define VM0()   asm volatile("s_waitcnt vmcnt(0)" ::: "memory")

  const int NP = (K >> 6) >> 1;
  stageB(0); stageA(0); stageB(1); stageA(1);
  VM6();
  BAR();

  for (int j = 0; j < NP; ++j) {
    const int t0 = 2*j, t1 = 2*j + 1, t2 = 2*j + 2, t3 = 2*j + 3;
    const bool more = (j + 1 < NP);
    LDA(0); LDB(t0 % 3, 0);
    if (more) stageB(t2);
    BAR(); LGKM0(); MFMA_Q(0); BAR();
    LDB(t0 % 3, 1);
    if (more) { stageA(t2); VM6(); } else { VM0(); }
    BAR(); LGKM0(); MFMA_Q(1); BAR();
    LDA(1); LDB(t1 % 3, 0);
    if (more) stageB(t3);
    BAR(); LGKM0(); MFMA_Q(0); BAR();
    LDB(t1 % 3, 1);
    if (more) { stageA(t3); VM6(); } else { VM0(); }
    BAR(); LGKM0(); MFMA_Q(1); BAR();
  }
#undef MFMA_Q
#undef BAR
#undef LGKM0
#undef VM6
#undef VM0

  #pragma unroll
  for (int mf = 0; mf < 4; ++mf) {
    const int rbase = row0 + wm*64 + mf*16 + (lane>>4)*4;
    #pragma unroll
    for (int nf = 0; nf < 4; ++nf) {
      const int c = col0 + wn*64 + nf*16 + (lane&15);
      #pragma unroll
      for (int i = 0; i < 4; ++i) {
        const int rr = rbase + i;
        out0[(size_t)rr*N + c] = acc[mf][nf][i] + bias[c] + resid[(size_t)rr*N + c];
      }
    }
  }
}

// ---------------- causal flash attention, swapped-operand 32x32 (unchanged) ----------------
__global__ __launch_bounds__(256)
void k_attn(const bf16_t* __restrict__ Q, const bf16_t* __restrict__ Kg,
            const bf16_t* __restrict__ Vt, bf16_t* __restrict__ O)
{
  __shared__ __align__(16) bf16_t Ks [64][72];
  __shared__ __align__(16) bf16_t Vts[64][72];
  __shared__ __align__(16) bf16_t Os [128][72];
  const int bh = blockIdx.y;
  const int pair = blockIdx.x;
  const int tid = threadIdx.x, lane = tid & 63, w = tid >> 6;
  const int ql = lane & 31, hi = lane >> 5;
  const int srow = tid >> 2;
  const int scol = (tid & 3) * 16;
  const bf16_t* Kgp = Kg + ((size_t)bh*T_ + srow)*D_ + scol;
  const bf16_t* Vtp = Vt + ((size_t)bh*D_ + srow)*T_ + scol;
  const int b = bh >> 4, h = bh & 15;

  for(int half=0; half<2; ++half){
    const int qt = half ? pair : (15 - pair);
    const int qbase = qt*128 + w*32;
    const int q = qbase + ql;

    v8bf qf[4];
    {
      const bf16_t* Qb = Q + ((size_t)bh*T_ + q)*D_ + hi*8;
      #pragma unroll
      for(int ds=0; ds<4; ds++)
        qf[ds] = *reinterpret_cast<const v8bf*>(Qb + ds*16);
    }

    f32x16 accO[2] = {};
    float mrun = -1e30f, lrun = 0.0f;
    const int NT = (qt + 1) * 2;

    v8bf kr0 = *reinterpret_cast<const v8bf*>(Kgp);
    v8bf kr1 = *reinterpret_cast<const v8bf*>(Kgp + 8);
    v8bf vr0 = *reinterpret_cast<const v8bf*>(Vtp);
    v8bf vr1 = *reinterpret_cast<const v8bf*>(Vtp + 8);

    for(int t=0; t<NT; t++){
      const int kv0 = t*64;
      *reinterpret_cast<v8bf*>(&Ks [srow][scol  ]) = kr0;
      *reinterpret_cast<v8bf*>(&Ks [srow][scol+8]) = kr1;
      *reinterpret_cast<v8bf*>(&Vts[srow][scol  ]) = vr0;
      *reinterpret_cast<v8bf*>(&Vts[srow][scol+8]) = vr1;
      __syncthreads();
      if(t+1 < NT){
        const size_t kn = (size_t)(kv0 + 64);
        kr0 = *reinterpret_cast<const v8bf*>(Kgp + kn*D_);
        kr1 = *reinterpret_cast<const v8bf*>(Kgp + kn*D_ + 8);
        vr0 = *reinterpret_cast<const v8bf*>(Vtp + kn);
        vr1 = *reinterpret_cast<const v8bf*>(Vtp + kn + 8);
      }

      if(kv0 <= qbase + 31){
        f32x16 sT[2] = {};
        #pragma unroll
        for(int kvh=0; kvh<2; kvh++)
          #pragma unroll
          for(int ds=0; ds<4; ds++){
            v8bf kf = *reinterpret_cast<const v8bf*>(&Ks[kvh*32 + ql][ds*16 + hi*8]);
            sT[kvh] = __builtin_amdgcn_mfma_f32_32x32x16_bf16(kf, qf[ds], sT[kvh], 0,0,0);
          }

        if(kv0 + 63 > qbase){
          const int qrel = q - kv0 - hi*4;
          #pragma unroll
          for(int kvh=0; kvh<2; kvh++)
            #pragma unroll
            for(int r=0; r<16; r++){
              const int c = kvh*32 + (r&3) + 8*(r>>2);
              if(c > qrel) sT[kvh][r] = -1e30f;
            }
        }

        float pm = sT[0][0];
        #pragma unroll
        for(int r=1; r<16; r++) pm = fmaxf(pm, sT[0][r]);
        #pragma unroll
        for(int r=0; r<16; r++) pm = fmaxf(pm, sT[1][r]);
        pm = fmaxf(pm, __shfl_xor(pm, 32));

        if(__any(pm - mrun > 8.0f)){
          const float mnew = fmaxf(mrun, pm);
          const float corr = __builtin_amdgcn_exp2f(mrun - mnew);
          mrun = mnew;
          lrun *= corr;
          #pragma unroll
          for(int dh=0; dh<2; dh++)
            #pragma unroll
            for(int r=0; r<16; r++) accO[dh][r] *= corr;
        }

        float rs = 0.0f;
        #pragma unroll
        for(int kvh=0; kvh<2; kvh++)
          #pragma unroll
          for(int r=0; r<16; r++){
            float p = __builtin_amdgcn_exp2f(sT[kvh][r] - mrun);
            sT[kvh][r] = p;
            rs += p;
          }
        rs += __shfl_xor(rs, 32);
        lrun += rs;

        v8bf pfrag[4];
        #pragma unroll
        for(int s4=0; s4<4; s4++){
          const int kvh = s4>>1, bb = (s4&1)*8;
          uint32_t wa = cvt_pk_bf16(sT[kvh][bb+0], sT[kvh][bb+1]);
          uint32_t wb = cvt_pk_bf16(sT[kvh][bb+2], sT[kvh][bb+3]);
          uint32_t wc = cvt_pk_bf16(sT[kvh][bb+4], sT[kvh][bb+5]);
          uint32_t wd = cvt_pk_bf16(sT[kvh][bb+6], sT[kvh][bb+7]);
          uint32_t xwa = (uint32_t)__shfl_xor((int)wa, 32);
          uint32_t xwb = (uint32_t)__shfl_xor((int)wb, 32);
          uint32_t xwc = (uint32_t)__shfl_xor((int)wc, 32);
          uint32_t xwd = (uint32_t)__shfl_xor((int)wd, 32);
          union { uint32_t u[4]; v8bf v; } pk;
          pk.u[0] = hi ? xwc : wa;
          pk.u[1] = hi ? xwd : wb;
          pk.u[2] = hi ? wc  : xwa;
          pk.u[3] = hi ? wd  : xwb;
          pfrag[s4] = pk.v;
        }

        #pragma unroll
        for(int dh=0; dh<2; dh++)
          #pragma unroll
          for(int s4=0; s4<4; s4++){
            v8bf vf = *reinterpret_cast<const v8bf*>(&Vts[dh*32 + ql][s4*16 + hi*8]);
            accO[dh] = __builtin_amdgcn_mfma_f32_32x32x16_bf16(vf, pfrag[s4], accO[dh], 0,0,0);
          }
      }
      __syncthreads();
    }

    const float inv = 1.0f / lrun;
    #pragma unroll
    for(int dh=0; dh<2; dh++)
      #pragma unroll
      for(int rg=0; rg<4; rg++){
        uint32_t lo_ = cvt_pk_bf16(accO[dh][rg*4+0]*inv, accO[dh][rg*4+1]*inv);
        uint32_t hi_ = cvt_pk_bf16(accO[dh][rg*4+2]*inv, accO[dh][rg*4+3]*inv);
        uint2 w2; w2.x = lo_; w2.y = hi_;
        *reinterpret_cast<uint2*>(&Os[w*32 + ql][dh*32 + rg*8 + hi*4]) = w2;
      }
    __syncthreads();
    const int orow = tid >> 1, ocol = (tid & 1) * 32;
    bf16_t* Og = O + ((size_t)(b*T_ + qt*128 + orow))*C_ + h*64 + ocol;
    #pragma unroll
    for(int j=0;j<4;j++)
      *reinterpret_cast<v8bf*>(Og + j*8) = *reinterpret_cast<const v8bf*>(&Os[orow][ocol + j*8]);
    __syncthreads();
  }
}

// ---------------- launch ----------------
extern "C" void kernel_launch(void* const* d_in, const int* in_sizes, int n_in,
                              void* d_out, int out_size, void* d_ws, size_t ws_size,
                              hipStream_t stream) {
  const float* x      = (const float*)d_in[0];
  const float* w_qkv  = (const float*)d_in[1];
  const float* w_proj = (const float*)d_in[2];
  const float* b_proj = (const float*)d_in[3];
  const float* w1     = (const float*)d_in[4];
  const float* b1     = (const float*)d_in[5];
  const float* w2     = (const float*)d_in[6];
  const float* b2     = (const float*)d_in[7];
  const float* gamma1 = (const float*)d_in[8];
  const float* beta1  = (const float*)d_in[9];
  const float* gamma2 = (const float*)d_in[10];
  const float* beta2  = (const float*)d_in[11];

  char* ws = (char*)d_ws;
  bf16_t* wqkv_t  = (bf16_t*)(ws + 0);           // 3072x1024
  bf16_t* wproj_t = (bf16_t*)(ws + 6291456);     // 1024x1024
  bf16_t* w1_t    = (bf16_t*)(ws + 8388608);     // 4096x1024
  bf16_t* w2_t    = (bf16_t*)(ws + 16777216);    // 1024x4096
  bf16_t* qb      = (bf16_t*)(ws + 25165824);    // [B,H,T,D]
  bf16_t* kb      = (bf16_t*)(ws + 41943040);    // [B,H,T,D]
  bf16_t* vtb     = (bf16_t*)(ws + 58720256);    // [B,H,D,T]
  bf16_t* obuf    = (bf16_t*)(ws + 75497472);    // [B,T,C]; FFN2 partial p0
  bf16_t* hb      = (bf16_t*)(ws + 92274688);    // [M,C]; FFN2 partial p1
  bf16_t* gb      = (bf16_t*)(ws + 25165824);    // [M,4C] bf16 (reuses q..o)
  float*  x2      = (float*)d_out;               // x after attn residual (aliases out)

  k_transpose_all<<<12288, dim3(32,8), 0, stream>>>(w_qkv, wqkv_t, w_proj, wproj_t,
                                                    w1, w1_t, w2, w2_t);

  k_layernorm<<<M_, 256, 0, stream>>>(x, gamma1, beta1, hb);

  // QKV: persistent 256x256 fat-phase, tc=384 tiles over 256 blocks
  k_gemm9<0><<<dim3(256, 1, 1), 512, 0, stream>>>(hb, wqkv_t, nullptr, nullptr,
                                                  qb, kb, vtb, 3072, 1024, 1024, 12, 384);
  k_attn<<<dim3(8, B_*H_), 256, 0, stream>>>(qb, kb, vtb, obuf);

  // proj: 256x128 4-phase, 256 blocks
  k_gemm8<<<dim3(8, 32), 512, 0, stream>>>(obuf, wproj_t, b_proj, x,
                                           x2, 1024, 1024, 8);
  k_layernorm<<<M_, 256, 0, stream>>>(x2, gamma2, beta2, hb);

  // FFN1: persistent 256x256 fat-phase, tc=512 tiles over 256 blocks (2 each)
  k_gemm9<2><<<dim3(256, 1, 1), 512, 0, stream>>>(hb, w1_t, b1, nullptr,
                                                  gb, nullptr, nullptr, 4096, 1024, 1024, 16, 512);
  // FFN2: split-K=2 on 256x256 fat-phase, tc=128 tiles per piece, 128 blocks x 2 z
  k_gemm9<4><<<dim3(128, 1, 2), 512, 0, stream>>>(gb, w2_t, nullptr, nullptr,
                                                  obuf, hb, nullptr, 1024, 4096, 2048, 4, 128);
  k_add2<<<M_, 256, 0, stream>>>(obuf, hb, b2, x2);
}

// Round 16
// 374.378 us; speedup vs baseline: 1.1892x; 1.1892x over previous
//
#include <hip/hip_runtime.h>
#include <hip/hip_bf16.h>
#include <cstdint>
#include <cstddef>

#define B_ 4
#define T_ 2048
#define C_ 1024
#define H_ 16
#define D_ 64
#define M_ (B_*T_)   // 8192 rows

using bf16_t = __hip_bfloat16;
typedef __bf16 v8bf __attribute__((ext_vector_type(8)));
typedef float  v4f  __attribute__((ext_vector_type(4)));
typedef float  f32x16 __attribute__((ext_vector_type(16)));

// 1/sqrt(D) * log2(e): folded into Q at the QKV epilogue; softmax in exp2 domain.
#define QSCALE (0.125f * 1.44269504088896340736f)

static __device__ __forceinline__ bf16_t f2bf(float v){ return __float2bfloat16(v); }

// async global->LDS, 16B per lane. LDS dest is wave-uniform base + lane*16.
static __device__ __forceinline__ void glds16(const bf16_t* g, bf16_t* l){
  __builtin_amdgcn_global_load_lds((__attribute__((address_space(1))) void*)g,
                                   (__attribute__((address_space(3))) void*)l, 16, 0, 0);
}

static __device__ __forceinline__ uint32_t cvt_pk_bf16(float lo, float hi){
  uint32_t w;
  asm("v_cvt_pk_bf16_f32 %0, %1, %2" : "=v"(w) : "v"(lo), "v"(hi));
  return w;
}

// tanh-form GELU in exp2 domain (branch-free, inf-safe).
static __device__ __forceinline__ float gelu_fast(float x){
  const float u = __builtin_fmaf(0.044715f * x * x, x, x);
  const float e = __builtin_amdgcn_exp2f(2.3021256637f * u);
  return x - x * __builtin_amdgcn_rcpf(1.0f + e);
}

// ---------------- merged transpose + cast fp32[K][N] -> bf16[N][K], 4 jobs ----------------
__global__ void k_transpose_all(const float* __restrict__ in0, bf16_t* __restrict__ out0,
                                const float* __restrict__ in1, bf16_t* __restrict__ out1,
                                const float* __restrict__ in2, bf16_t* __restrict__ out2,
                                const float* __restrict__ in3, bf16_t* __restrict__ out3){
  __shared__ float tile[32][33];
  const int bid = blockIdx.x;
  const float* in; bf16_t* out; int K, N, lb;
  if (bid < 3072)      { in=in0; out=out0; K=1024; N=3072; lb=bid; }
  else if (bid < 4096) { in=in1; out=out1; K=1024; N=1024; lb=bid-3072; }
  else if (bid < 8192) { in=in2; out=out2; K=1024; N=4096; lb=bid-4096; }
  else                 { in=in3; out=out3; K=4096; N=1024; lb=bid-8192; }
  const int nbx = N >> 5;
  const int k0 = (lb / nbx) * 32, n0 = (lb % nbx) * 32;
  const int tx = threadIdx.x, ty = threadIdx.y; // 32 x 8
  #pragma unroll
  for(int j=0;j<32;j+=8) tile[ty+j][tx] = in[(size_t)(k0+ty+j)*N + n0+tx];
  __syncthreads();
  #pragma unroll
  for(int j=0;j<32;j+=8) out[(size_t)(n0+ty+j)*K + k0+tx] = f2bf(tile[tx][ty+j]);
}

// ---------------- LayerNorm fp32 row -> bf16 row ----------------
__global__ __launch_bounds__(256) void k_layernorm(const float* __restrict__ x,
                                                   const float* __restrict__ gamma,
                                                   const float* __restrict__ beta,
                                                   bf16_t* __restrict__ out){
  int row = blockIdx.x;
  int tid = threadIdx.x;
  const float4 v = reinterpret_cast<const float4*>(x + (size_t)row*C_)[tid];
  float s  = v.x+v.y+v.z+v.w;
  float ss = v.x*v.x+v.y*v.y+v.z*v.z+v.w*v.w;
  #pragma unroll
  for(int m=1;m<64;m<<=1){ s += __shfl_xor(s,m); ss += __shfl_xor(ss,m); }
  __shared__ float sbuf[4], ssbuf[4];
  int wid = tid>>6, lane = tid&63;
  if(lane==0){ sbuf[wid]=s; ssbuf[wid]=ss; }
  __syncthreads();
  s  = sbuf[0]+sbuf[1]+sbuf[2]+sbuf[3];
  ss = ssbuf[0]+ssbuf[1]+ssbuf[2]+ssbuf[3];
  float mean = s * (1.0f/C_);
  float var  = ss * (1.0f/C_) - mean*mean;
  float rstd = rsqrtf(var + 1e-3f);
  const float4 g = reinterpret_cast<const float4*>(gamma)[tid];
  const float4 b = reinterpret_cast<const float4*>(beta)[tid];
  union { ushort4 u; bf16_t h[4]; } pk;
  pk.h[0] = f2bf(g.x*(v.x-mean)*rstd + b.x);
  pk.h[1] = f2bf(g.y*(v.y-mean)*rstd + b.y);
  pk.h[2] = f2bf(g.z*(v.z-mean)*rstd + b.z);
  pk.h[3] = f2bf(g.w*(v.w-mean)*rstd + b.w);
  *reinterpret_cast<ushort4*>(out + (size_t)row*C_ + tid*4) = pk.u;
}

// ---------------- GEMM A: 256x256, BK=64, 8 waves (2Mx4N), 8-phase, PERSISTENT ----------
// (r13 schedule, best measured: read spread {12,4,8,0}; loop-top vmcnt(6))
// MODE 0: QKV split epilogue; MODE 2: bias+GELU(tanh-form)->bf16.
template<int MODE>
__global__ __launch_bounds__(512, 1)
void k_gemm9(const bf16_t* __restrict__ A, const bf16_t* __restrict__ Bt,
             const float* __restrict__ bias, const float* resid,
             void* out0, void* out1, void* out2,
             int N, int ld, int klen, int gx, int tc)
{
  __shared__ __align__(16) bf16_t As[2][2][128*64];
  __shared__ __align__(16) bf16_t Bs[2][2][128*64];
  const int tid = threadIdx.x, lane = tid & 63, w = tid >> 6;
  const int wm = w >> 2, wn = w & 3;
  const int koff = blockIdx.z * klen;

  const int sswz = ((lane & 7) ^ ((lane >> 3) & 7)) * 8;
  const int srow = w * 8 + (lane >> 3);

  int row0, col0;
  const bf16_t *Agb, *Bgb;
  auto set_tile = [&](int tile){
    const int swz = (tile & 7) * (tc >> 3) + (tile >> 3);   // bijective, tc%8==0
    const int ct = swz % gx, rt = swz / gx;
    row0 = rt * 256; col0 = ct * 256;
    Agb = A  + (size_t)(row0 + srow) * ld + koff + sswz;
    Bgb = Bt + (size_t)(col0 + srow) * ld + koff + sswz;
  };

  auto stageA = [&](int tt, int hh){
    const bf16_t* src = Agb + (size_t)(hh * 128) * ld + tt * 64;
    bf16_t* dst = &As[tt & 1][hh][w * 512];
    glds16(src, dst);
    glds16(src + (size_t)64 * ld, dst + 4096);
  };
  auto stageB = [&](int tt, int hh){
    const bf16_t* src = Bgb + (size_t)(hh * 128) * ld + tt * 64;
    bf16_t* dst = &Bs[tt & 1][hh][w * 512];
    glds16(src, dst);
    glds16(src + (size_t)64 * ld, dst + 4096);
  };
  auto stage_prologue = [&](){
    stageA(0,0); stageA(0,1); stageB(0,0); stageB(0,1);
    stageB(1,0); stageB(1,1); stageA(1,0);
  };

  v8bf af[4][2], bfv[4][2];
  v4f acc[8][4];

  auto LDA = [&](int bb, int mh){
    const bf16_t* base = &As[bb][wm][0];
    #pragma unroll
    for (int m = 0; m < 4; ++m)
      #pragma unroll
      for (int kk = 0; kk < 2; ++kk) {
        const int r  = mh*64 + m*16 + (lane & 15);
        const int sl = (kk*4 + (lane >> 4)) ^ (lane & 7);
        af[m][kk] = *reinterpret_cast<const v8bf*>(base + r*64 + sl*8);
      }
  };
  auto LDB4 = [&](int bb, int nh){
    const bf16_t* base = &Bs[bb][wn >> 1][0];
    #pragma unroll
    for (int n = 0; n < 2; ++n)
      #pragma unroll
      for (int kk = 0; kk < 2; ++kk) {
        const int r  = (wn & 1)*64 + (nh*2+n)*16 + (lane & 15);
        const int sl = (kk*4 + (lane >> 4)) ^ (lane & 7);
        bfv[nh*2+n][kk] = *reinterpret_cast<const v8bf*>(base + r*64 + sl*8);
      }
  };

#define MFMA_Q(mh_, nh_) \
  __builtin_amdgcn_s_setprio(1); \
  _Pragma("unroll") \
  for (int kk = 0; kk < 2; ++kk) \
    _Pragma("unroll") \
    for (int m = 0; m < 4; ++m) \
      _Pragma("unroll") \
      for (int n = 0; n < 2; ++n) \
        acc[(mh_)*4+m][(nh_)*2+n] = __builtin_amdgcn_mfma_f32_16x16x32_bf16( \
            af[m][kk], bfv[(nh_)*2+n][kk], acc[(mh_)*4+m][(nh_)*2+n], 0,0,0); \
  __builtin_amdgcn_s_setprio(0);

#define BAR()   __builtin_amdgcn_s_barrier()
#define LGKM0() do { asm volatile("s_waitcnt lgkmcnt(0)" ::: "memory"); \
                     __builtin_amdgcn_sched_barrier(0); } while(0)

  const int NP = (klen >> 6) >> 1;
  int tile = blockIdx.x;
  set_tile(tile);
  stage_prologue();

  for (;;) {
    asm volatile("s_waitcnt vmcnt(6)" ::: "memory");   // drain this tile's K0 A+B only
    BAR();
    #pragma unroll
    for (int mf = 0; mf < 8; ++mf)
      #pragma unroll
      for (int nf = 0; nf < 4; ++nf)
        acc[mf][nf] = (v4f){0.f, 0.f, 0.f, 0.f};

    for (int j = 0; j < NP; ++j) {
      const int t2 = 2*j + 2, t3 = 2*j + 3;
      const bool more = (j + 1 < NP);
      // ---- ph1: 12 reads ----
      LDA(0, 0); LDB4(0, 0);
      stageA(2*j + 1, 1);
      BAR(); LGKM0(); MFMA_Q(0, 0); BAR();
      // ---- ph2: 4 reads ----
      LDB4(0, 1);
      if (more) stageB(t2, 0);
      BAR(); LGKM0(); MFMA_Q(0, 1); BAR();
      // ---- ph3: 8 reads ----
      LDA(0, 1);
      if (more) stageB(t2, 1);
      BAR(); LGKM0(); MFMA_Q(1, 0); BAR();
      // ---- ph4: 0 reads ----
      if (more) { stageA(t2, 0); asm volatile("s_waitcnt vmcnt(6)" ::: "memory"); }
      else      {                asm volatile("s_waitcnt vmcnt(0)" ::: "memory"); }
      BAR(); MFMA_Q(1, 1); BAR();
      // ---- ph5: 12 reads ----
      LDA(1, 0); LDB4(1, 0);
      if (more) stageA(t2, 1);
      BAR(); LGKM0(); MFMA_Q(0, 0); BAR();
      // ---- ph6: 4 reads ----
      LDB4(1, 1);
      if (more) stageB(t3, 0);
      BAR(); LGKM0(); MFMA_Q(0, 1); BAR();
      // ---- ph7: 8 reads ----
      LDA(1, 1);
      if (more) stageB(t3, 1);
      BAR(); LGKM0(); MFMA_Q(1, 0); BAR();
      // ---- ph8: 0 reads ----
      if (more) { stageA(t3, 0); asm volatile("s_waitcnt vmcnt(6)" ::: "memory"); }
      else      {                asm volatile("s_waitcnt vmcnt(0)" ::: "memory"); }
      BAR(); MFMA_Q(1, 1); BAR();
    }

    // issue next tile's prologue BEFORE the epilogue (HBM latency hides under it)
    const int erow0 = row0, ecol0 = col0;
    const int next = tile + (int)gridDim.x;
    const bool have_next = (next < tc);
    if (have_next) { set_tile(next); stage_prologue(); }

    #pragma unroll
    for (int mf = 0; mf < 8; ++mf) {
      const int rbase = erow0 + wm*128 + mf*16 + (lane>>4)*4;
      #pragma unroll
      for (int nf = 0; nf < 4; ++nf) {
        const int c = ecol0 + wn*64 + nf*16 + (lane&15);
        #pragma unroll
        for (int i = 0; i < 4; ++i) {
          const int rr = rbase + i;
          float v = acc[mf][nf][i];
          if constexpr(MODE==0){
            const int sec = c >> 10, cc = c & 1023;
            const int h = cc >> 6, d = cc & 63;
            const int b = rr >> 11, t = rr & 2047;
            if(sec==0)      ((bf16_t*)out0)[((size_t)(b*H_ + h)*T_ + t)*D_ + d] = f2bf(v * QSCALE);
            else if(sec==1) ((bf16_t*)out1)[((size_t)(b*H_ + h)*T_ + t)*D_ + d] = f2bf(v);
            else            ((bf16_t*)out2)[((size_t)(b*H_ + h)*D_ + d)*T_ + t] = f2bf(v);
          } else {  // MODE 2
            ((bf16_t*)out0)[(size_t)rr*N + c] = f2bf(gelu_fast(v + bias[c]));
          }
        }
      }
    }
    if (!have_next) break;
    tile = next;
  }
#undef MFMA_Q
#undef BAR
#undef LGKM0
}

// ---------------- GEMM B: 256x128 tile, BK=64, 8 waves, 4-phase ----------
// Used for proj (K=1024) and FFN2 (K=4096). Epilogue: fp32 out = acc + bias + resid
// (resid may alias out — per-element read-then-write in one lane).
__global__ __launch_bounds__(512, 1)
void k_gemm8(const bf16_t* __restrict__ A, const bf16_t* __restrict__ Bt,
             const float* __restrict__ bias, const float* resid,
             float* out0, int N, int K, int gx)
{
  __shared__ __align__(16) bf16_t As[2][256*64];
  __shared__ __align__(16) bf16_t Bs[3][128*64];
  const int tid = threadIdx.x, lane = tid & 63, w = tid >> 6;
  const int wm = w >> 1, wn = w & 1;

  const int nwg = gx * 32;
  const int orig = blockIdx.y * gx + blockIdx.x;
  const int swz = (orig & 7) * (nwg >> 3) + (orig >> 3);
  const int ct = swz % gx, rt = swz / gx;
  const int row0 = rt * 256, col0 = ct * 128;

  const int sswz = ((lane & 7) ^ ((lane >> 3) & 7)) * 8;
  const int srow = w * 8 + (lane >> 3);
  const bf16_t* Agb = A  + (size_t)(row0 + srow) * K + sswz;
  const bf16_t* Bgb = Bt + (size_t)(col0 + srow) * K + sswz;

  auto stageA = [&](int tt){
    const bf16_t* src = Agb + tt * 64;
    bf16_t* dst = &As[tt & 1][w * 512];
    #pragma unroll
    for (int i = 0; i < 4; ++i)
      glds16(src + (size_t)(i*64) * K, dst + i*4096);
  };
  auto stageB = [&](int tt){
    const bf16_t* src = Bgb + tt * 64;
    bf16_t* dst = &Bs[tt % 3][w * 512];
    #pragma unroll
    for (int i = 0; i < 2; ++i)
      glds16(src + (size_t)(i*64) * K, dst + i*4096);
  };

  v8bf af[4][2], bfv[4][2];
  v4f acc[4][4] = {};

  auto LDA = [&](int ab){
    const bf16_t* base = &As[ab][0];
    #pragma unroll
    for (int m = 0; m < 4; ++m)
      #pragma unroll
      for (int kk = 0; kk < 2; ++kk) {
        const int r  = wm*64 + m*16 + (lane & 15);
        const int sl = (kk*4 + (lane >> 4)) ^ (lane & 7);
        af[m][kk] = *reinterpret_cast<const v8bf*>(base + r*64 + sl*8);
      }
  };
  auto LDB = [&](int bb, int nh){
    const bf16_t* base = &Bs[bb][0];
    #pragma unroll
    for (int n = 0; n < 2; ++n)
      #pragma unroll
      for (int kk = 0; kk < 2; ++kk) {
        const int r  = wn*64 + (nh*2+n)*16 + (lane & 15);
        const int sl = (kk*4 + (lane >> 4)) ^ (lane & 7);
        bfv[nh*2+n][kk] = *reinterpret_cast<const v8bf*>(base + r*64 + sl*8);
      }
  };

#define MFMA_Q(nh_) \
  __builtin_amdgcn_s_setprio(1); \
  _Pragma("unroll") \
  for (int kk = 0; kk < 2; ++kk) \
    _Pragma("unroll") \
    for (int m = 0; m < 4; ++m) \
      _Pragma("unroll") \
      for (int n = 0; n < 2; ++n) \
        acc[m][(nh_)*2+n] = __builtin_amdgcn_mfma_f32_16x16x32_bf16( \
            af[m][kk], bfv[(nh_)*2+n][kk], acc[m][(nh_)*2+n], 0,0,0); \
  __builtin_amdgcn_s_setprio(0);

#define BAR()   __builtin_amdgcn_s_barrier()
#define LGKM0() do { asm volatile("s_waitcnt lgkmcnt(0)" ::: "memory"); \
                     __builtin_amdgcn_sched_barrier(0); } while(0)
#define VM6()   asm volatile("s_waitcnt vmcnt(6)" ::: "memory")
#define VM0()   asm volatile("s_waitcnt vmcnt(0)" ::: "memory")

  const int NP = (K >> 6) >> 1;
  stageB(0); stageA(0); stageB(1); stageA(1);
  VM6();
  BAR();

  for (int j = 0; j < NP; ++j) {
    const int t0 = 2*j, t1 = 2*j + 1, t2 = 2*j + 2, t3 = 2*j + 3;
    const bool more = (j + 1 < NP);
    LDA(0); LDB(t0 % 3, 0);
    if (more) stageB(t2);
    BAR(); LGKM0(); MFMA_Q(0); BAR();
    LDB(t0 % 3, 1);
    if (more) { stageA(t2); VM6(); } else { VM0(); }
    BAR(); LGKM0(); MFMA_Q(1); BAR();
    LDA(1); LDB(t1 % 3, 0);
    if (more) stageB(t3);
    BAR(); LGKM0(); MFMA_Q(0); BAR();
    LDB(t1 % 3, 1);
    if (more) { stageA(t3); VM6(); } else { VM0(); }
    BAR(); LGKM0(); MFMA_Q(1); BAR();
  }
#undef MFMA_Q
#undef BAR
#undef LGKM0
#undef VM6
#undef VM0

  #pragma unroll
  for (int mf = 0; mf < 4; ++mf) {
    const int rbase = row0 + wm*64 + mf*16 + (lane>>4)*4;
    #pragma unroll
    for (int nf = 0; nf < 4; ++nf) {
      const int c = col0 + wn*64 + nf*16 + (lane&15);
      #pragma unroll
      for (int i = 0; i < 4; ++i) {
        const int rr = rbase + i;
        out0[(size_t)rr*N + c] = acc[mf][nf][i] + bias[c] + resid[(size_t)rr*N + c];
      }
    }
  }
}

// ---------------- causal flash attention, swapped-operand 32x32 (unchanged) ----------------
__global__ __launch_bounds__(256)
void k_attn(const bf16_t* __restrict__ Q, const bf16_t* __restrict__ Kg,
            const bf16_t* __restrict__ Vt, bf16_t* __restrict__ O)
{
  __shared__ __align__(16) bf16_t Ks [64][72];
  __shared__ __align__(16) bf16_t Vts[64][72];
  __shared__ __align__(16) bf16_t Os [128][72];
  const int bh = blockIdx.y;
  const int pair = blockIdx.x;
  const int tid = threadIdx.x, lane = tid & 63, w = tid >> 6;
  const int ql = lane & 31, hi = lane >> 5;
  const int srow = tid >> 2;
  const int scol = (tid & 3) * 16;
  const bf16_t* Kgp = Kg + ((size_t)bh*T_ + srow)*D_ + scol;
  const bf16_t* Vtp = Vt + ((size_t)bh*D_ + srow)*T_ + scol;
  const int b = bh >> 4, h = bh & 15;

  for(int half=0; half<2; ++half){
    const int qt = half ? pair : (15 - pair);
    const int qbase = qt*128 + w*32;
    const int q = qbase + ql;

    v8bf qf[4];
    {
      const bf16_t* Qb = Q + ((size_t)bh*T_ + q)*D_ + hi*8;
      #pragma unroll
      for(int ds=0; ds<4; ds++)
        qf[ds] = *reinterpret_cast<const v8bf*>(Qb + ds*16);
    }

    f32x16 accO[2] = {};
    float mrun = -1e30f, lrun = 0.0f;
    const int NT = (qt + 1) * 2;

    v8bf kr0 = *reinterpret_cast<const v8bf*>(Kgp);
    v8bf kr1 = *reinterpret_cast<const v8bf*>(Kgp + 8);
    v8bf vr0 = *reinterpret_cast<const v8bf*>(Vtp);
    v8bf vr1 = *reinterpret_cast<const v8bf*>(Vtp + 8);

    for(int t=0; t<NT; t++){
      const int kv0 = t*64;
      *reinterpret_cast<v8bf*>(&Ks [srow][scol  ]) = kr0;
      *reinterpret_cast<v8bf*>(&Ks [srow][scol+8]) = kr1;
      *reinterpret_cast<v8bf*>(&Vts[srow][scol  ]) = vr0;
      *reinterpret_cast<v8bf*>(&Vts[srow][scol+8]) = vr1;
      __syncthreads();
      if(t+1 < NT){
        const size_t kn = (size_t)(kv0 + 64);
        kr0 = *reinterpret_cast<const v8bf*>(Kgp + kn*D_);
        kr1 = *reinterpret_cast<const v8bf*>(Kgp + kn*D_ + 8);
        vr0 = *reinterpret_cast<const v8bf*>(Vtp + kn);
        vr1 = *reinterpret_cast<const v8bf*>(Vtp + kn + 8);
      }

      if(kv0 <= qbase + 31){
        f32x16 sT[2] = {};
        #pragma unroll
        for(int kvh=0; kvh<2; kvh++)
          #pragma unroll
          for(int ds=0; ds<4; ds++){
            v8bf kf = *reinterpret_cast<const v8bf*>(&Ks[kvh*32 + ql][ds*16 + hi*8]);
            sT[kvh] = __builtin_amdgcn_mfma_f32_32x32x16_bf16(kf, qf[ds], sT[kvh], 0,0,0);
          }

        if(kv0 + 63 > qbase){
          const int qrel = q - kv0 - hi*4;
          #pragma unroll
          for(int kvh=0; kvh<2; kvh++)
            #pragma unroll
            for(int r=0; r<16; r++){
              const int c = kvh*32 + (r&3) + 8*(r>>2);
              if(c > qrel) sT[kvh][r] = -1e30f;
            }
        }

        float pm = sT[0][0];
        #pragma unroll
        for(int r=1; r<16; r++) pm = fmaxf(pm, sT[0][r]);
        #pragma unroll
        for(int r=0; r<16; r++) pm = fmaxf(pm, sT[1][r]);
        pm = fmaxf(pm, __shfl_xor(pm, 32));

        if(__any(pm - mrun > 8.0f)){
          const float mnew = fmaxf(mrun, pm);
          const float corr = __builtin_amdgcn_exp2f(mrun - mnew);
          mrun = mnew;
          lrun *= corr;
          #pragma unroll
          for(int dh=0; dh<2; dh++)
            #pragma unroll
            for(int r=0; r<16; r++) accO[dh][r] *= corr;
        }

        float rs = 0.0f;
        #pragma unroll
        for(int kvh=0; kvh<2; kvh++)
          #pragma unroll
          for(int r=0; r<16; r++){
            float p = __builtin_amdgcn_exp2f(sT[kvh][r] - mrun);
            sT[kvh][r] = p;
            rs += p;
          }
        rs += __shfl_xor(rs, 32);
        lrun += rs;

        v8bf pfrag[4];
        #pragma unroll
        for(int s4=0; s4<4; s4++){
          const int kvh = s4>>1, bb = (s4&1)*8;
          uint32_t wa = cvt_pk_bf16(sT[kvh][bb+0], sT[kvh][bb+1]);
          uint32_t wb = cvt_pk_bf16(sT[kvh][bb+2], sT[kvh][bb+3]);
          uint32_t wc = cvt_pk_bf16(sT[kvh][bb+4], sT[kvh][bb+5]);
          uint32_t wd = cvt_pk_bf16(sT[kvh][bb+6], sT[kvh][bb+7]);
          uint32_t xwa = (uint32_t)__shfl_xor((int)wa, 32);
          uint32_t xwb = (uint32_t)__shfl_xor((int)wb, 32);
          uint32_t xwc = (uint32_t)__shfl_xor((int)wc, 32);
          uint32_t xwd = (uint32_t)__shfl_xor((int)wd, 32);
          union { uint32_t u[4]; v8bf v; } pk;
          pk.u[0] = hi ? xwc : wa;
          pk.u[1] = hi ? xwd : wb;
          pk.u[2] = hi ? wc  : xwa;
          pk.u[3] = hi ? wd  : xwb;
          pfrag[s4] = pk.v;
        }

        #pragma unroll
        for(int dh=0; dh<2; dh++)
          #pragma unroll
          for(int s4=0; s4<4; s4++){
            v8bf vf = *reinterpret_cast<const v8bf*>(&Vts[dh*32 + ql][s4*16 + hi*8]);
            accO[dh] = __builtin_amdgcn_mfma_f32_32x32x16_bf16(vf, pfrag[s4], accO[dh], 0,0,0);
          }
      }
      __syncthreads();
    }

    const float inv = 1.0f / lrun;
    #pragma unroll
    for(int dh=0; dh<2; dh++)
      #pragma unroll
      for(int rg=0; rg<4; rg++){
        uint32_t lo_ = cvt_pk_bf16(accO[dh][rg*4+0]*inv, accO[dh][rg*4+1]*inv);
        uint32_t hi_ = cvt_pk_bf16(accO[dh][rg*4+2]*inv, accO[dh][rg*4+3]*inv);
        uint2 w2; w2.x = lo_; w2.y = hi_;
        *reinterpret_cast<uint2*>(&Os[w*32 + ql][dh*32 + rg*8 + hi*4]) = w2;
      }
    __syncthreads();
    const int orow = tid >> 1, ocol = (tid & 1) * 32;
    bf16_t* Og = O + ((size_t)(b*T_ + qt*128 + orow))*C_ + h*64 + ocol;
    #pragma unroll
    for(int j=0;j<4;j++)
      *reinterpret_cast<v8bf*>(Og + j*8) = *reinterpret_cast<const v8bf*>(&Os[orow][ocol + j*8]);
    __syncthreads();
  }
}

// ---------------- launch ----------------
extern "C" void kernel_launch(void* const* d_in, const int* in_sizes, int n_in,
                              void* d_out, int out_size, void* d_ws, size_t ws_size,
                              hipStream_t stream) {
  const float* x      = (const float*)d_in[0];
  const float* w_qkv  = (const float*)d_in[1];
  const float* w_proj = (const float*)d_in[2];
  const float* b_proj = (const float*)d_in[3];
  const float* w1     = (const float*)d_in[4];
  const float* b1     = (const float*)d_in[5];
  const float* w2     = (const float*)d_in[6];
  const float* b2     = (const float*)d_in[7];
  const float* gamma1 = (const float*)d_in[8];
  const float* beta1  = (const float*)d_in[9];
  const float* gamma2 = (const float*)d_in[10];
  const float* beta2  = (const float*)d_in[11];

  char* ws = (char*)d_ws;
  bf16_t* wqkv_t  = (bf16_t*)(ws + 0);           // 3072x1024
  bf16_t* wproj_t = (bf16_t*)(ws + 6291456);     // 1024x1024
  bf16_t* w1_t    = (bf16_t*)(ws + 8388608);     // 4096x1024
  bf16_t* w2_t    = (bf16_t*)(ws + 16777216);    // 1024x4096
  bf16_t* qb      = (bf16_t*)(ws + 25165824);    // [B,H,T,D]
  bf16_t* kb      = (bf16_t*)(ws + 41943040);    // [B,H,T,D]
  bf16_t* vtb     = (bf16_t*)(ws + 58720256);    // [B,H,D,T]
  bf16_t* obuf    = (bf16_t*)(ws + 75497472);    // [B,T,C]
  bf16_t* hb      = (bf16_t*)(ws + 92274688);    // [M,C] bf16
  bf16_t* gb      = (bf16_t*)(ws + 25165824);    // [M,4C] bf16 (reuses q..o)
  float*  x2      = (float*)d_out;               // x after attn residual (aliases out)

  k_transpose_all<<<12288, dim3(32,8), 0, stream>>>(w_qkv, wqkv_t, w_proj, wproj_t,
                                                    w1, w1_t, w2, w2_t);

  k_layernorm<<<M_, 256, 0, stream>>>(x, gamma1, beta1, hb);

  // QKV: persistent 256x256 8-phase, tc=384 tiles over 256 blocks
  k_gemm9<0><<<dim3(256, 1, 1), 512, 0, stream>>>(hb, wqkv_t, nullptr, nullptr,
                                                  qb, kb, vtb, 3072, 1024, 1024, 12, 384);
  k_attn<<<dim3(8, B_*H_), 256, 0, stream>>>(qb, kb, vtb, obuf);

  // proj: 256x128 4-phase, 256 blocks
  k_gemm8<<<dim3(8, 32), 512, 0, stream>>>(obuf, wproj_t, b_proj, x,
                                           x2, 1024, 1024, 8);
  k_layernorm<<<M_, 256, 0, stream>>>(x2, gamma2, beta2, hb);

  // FFN1: persistent 256x256 8-phase, tc=512 tiles over 256 blocks (2 each)
  k_gemm9<2><<<dim3(256, 1, 1), 512, 0, stream>>>(hb, w1_t, b1, nullptr,
                                                  gb, nullptr, nullptr, 4096, 1024, 1024, 16, 512);
  // FFN2: 256x128 4-phase, K=4096 deep, 256 blocks; fused +bias+resid (replaces
  // split-K partials + add2 pass)
  k_gemm8<<<dim3(8, 32), 512, 0, stream>>>(gb, w2_t, b2, x2,
                                           x2, 1024, 4096, 8);
}

// Round 17
// 367.279 us; speedup vs baseline: 1.2122x; 1.0193x over previous
//
#include <hip/hip_runtime.h>
#include <hip/hip_bf16.h>
#include <cstdint>
#include <cstddef>

#define B_ 4
#define T_ 2048
#define C_ 1024
#define H_ 16
#define D_ 64
#define M_ (B_*T_)   // 8192 rows

using bf16_t = __hip_bfloat16;
typedef __bf16 v8bf __attribute__((ext_vector_type(8)));
typedef float  v4f  __attribute__((ext_vector_type(4)));
typedef float  f32x16 __attribute__((ext_vector_type(16)));

// 1/sqrt(D) * log2(e): folded into Q at the QKV epilogue; softmax in exp2 domain.
#define QSCALE (0.125f * 1.44269504088896340736f)

static __device__ __forceinline__ bf16_t f2bf(float v){ return __float2bfloat16(v); }
static __device__ __forceinline__ float bfraw2f(unsigned short u){
  union { unsigned int i; float f; } c; c.i = ((unsigned int)u) << 16; return c.f;
}

// async global->LDS, 16B per lane. LDS dest is wave-uniform base + lane*16.
static __device__ __forceinline__ void glds16(const bf16_t* g, bf16_t* l){
  __builtin_amdgcn_global_load_lds((__attribute__((address_space(1))) void*)g,
                                   (__attribute__((address_space(3))) void*)l, 16, 0, 0);
}

static __device__ __forceinline__ uint32_t cvt_pk_bf16(float lo, float hi){
  uint32_t w;
  asm("v_cvt_pk_bf16_f32 %0, %1, %2" : "=v"(w) : "v"(lo), "v"(hi));
  return w;
}

// tanh-form GELU in exp2 domain (branch-free, inf-safe).
static __device__ __forceinline__ float gelu_fast(float x){
  const float u = __builtin_fmaf(0.044715f * x * x, x, x);
  const float e = __builtin_amdgcn_exp2f(2.3021256637f * u);
  return x - x * __builtin_amdgcn_rcpf(1.0f + e);
}

// -------- merged: 4 weight transposes (blocks 0..12287) + LN1 (blocks 12288..20479) --------
__global__ __launch_bounds__(256)
void k_prep(const float* __restrict__ in0, bf16_t* __restrict__ out0,
            const float* __restrict__ in1, bf16_t* __restrict__ out1,
            const float* __restrict__ in2, bf16_t* __restrict__ out2,
            const float* __restrict__ in3, bf16_t* __restrict__ out3,
            const float* __restrict__ x,  const float* __restrict__ gamma,
            const float* __restrict__ beta, bf16_t* __restrict__ hb){
  const int bid = blockIdx.x;
  const int tid = threadIdx.x;
  if (bid < 12288) {   // transpose+cast fp32[K][N] -> bf16[N][K]
    __shared__ float tile[32][33];
    const float* in; bf16_t* out; int K, N, lb;
    if (bid < 3072)      { in=in0; out=out0; K=1024; N=3072; lb=bid; }
    else if (bid < 4096) { in=in1; out=out1; K=1024; N=1024; lb=bid-3072; }
    else if (bid < 8192) { in=in2; out=out2; K=1024; N=4096; lb=bid-4096; }
    else                 { in=in3; out=out3; K=4096; N=1024; lb=bid-8192; }
    const int nbx = N >> 5;
    const int k0 = (lb / nbx) * 32, n0 = (lb % nbx) * 32;
    const int tx = tid & 31, ty = tid >> 5;   // 32 x 8
    #pragma unroll
    for(int j=0;j<32;j+=8) tile[ty+j][tx] = in[(size_t)(k0+ty+j)*N + n0+tx];
    __syncthreads();
    #pragma unroll
    for(int j=0;j<32;j+=8) out[(size_t)(n0+ty+j)*K + k0+tx] = f2bf(tile[tx][ty+j]);
  } else {             // LayerNorm1 row -> bf16
    const int row = bid - 12288;
    const float4 v = reinterpret_cast<const float4*>(x + (size_t)row*C_)[tid];
    float s  = v.x+v.y+v.z+v.w;
    float ss = v.x*v.x+v.y*v.y+v.z*v.z+v.w*v.w;
    #pragma unroll
    for(int m=1;m<64;m<<=1){ s += __shfl_xor(s,m); ss += __shfl_xor(ss,m); }
    __shared__ float sbuf[4], ssbuf[4];
    const int wid = tid>>6, lane = tid&63;
    if(lane==0){ sbuf[wid]=s; ssbuf[wid]=ss; }
    __syncthreads();
    s  = sbuf[0]+sbuf[1]+sbuf[2]+sbuf[3];
    ss = ssbuf[0]+ssbuf[1]+ssbuf[2]+ssbuf[3];
    const float mean = s * (1.0f/C_);
    const float var  = ss * (1.0f/C_) - mean*mean;
    const float rstd = rsqrtf(var + 1e-3f);
    const float4 g = reinterpret_cast<const float4*>(gamma)[tid];
    const float4 b = reinterpret_cast<const float4*>(beta)[tid];
    union { ushort4 u; bf16_t h[4]; } pk;
    pk.h[0] = f2bf(g.x*(v.x-mean)*rstd + b.x);
    pk.h[1] = f2bf(g.y*(v.y-mean)*rstd + b.y);
    pk.h[2] = f2bf(g.z*(v.z-mean)*rstd + b.z);
    pk.h[3] = f2bf(g.w*(v.w-mean)*rstd + b.w);
    *reinterpret_cast<ushort4*>(hb + (size_t)row*C_ + tid*4) = pk.u;
  }
}

// ---------------- LayerNorm fp32 row -> bf16 row (LN2) ----------------
__global__ __launch_bounds__(256) void k_layernorm(const float* __restrict__ x,
                                                   const float* __restrict__ gamma,
                                                   const float* __restrict__ beta,
                                                   bf16_t* __restrict__ out){
  int row = blockIdx.x;
  int tid = threadIdx.x;
  const float4 v = reinterpret_cast<const float4*>(x + (size_t)row*C_)[tid];
  float s  = v.x+v.y+v.z+v.w;
  float ss = v.x*v.x+v.y*v.y+v.z*v.z+v.w*v.w;
  #pragma unroll
  for(int m=1;m<64;m<<=1){ s += __shfl_xor(s,m); ss += __shfl_xor(ss,m); }
  __shared__ float sbuf[4], ssbuf[4];
  int wid = tid>>6, lane = tid&63;
  if(lane==0){ sbuf[wid]=s; ssbuf[wid]=ss; }
  __syncthreads();
  s  = sbuf[0]+sbuf[1]+sbuf[2]+sbuf[3];
  ss = ssbuf[0]+ssbuf[1]+ssbuf[2]+ssbuf[3];
  float mean = s * (1.0f/C_);
  float var  = ss * (1.0f/C_) - mean*mean;
  float rstd = rsqrtf(var + 1e-3f);
  const float4 g = reinterpret_cast<const float4*>(gamma)[tid];
  const float4 b = reinterpret_cast<const float4*>(beta)[tid];
  union { ushort4 u; bf16_t h[4]; } pk;
  pk.h[0] = f2bf(g.x*(v.x-mean)*rstd + b.x);
  pk.h[1] = f2bf(g.y*(v.y-mean)*rstd + b.y);
  pk.h[2] = f2bf(g.z*(v.z-mean)*rstd + b.z);
  pk.h[3] = f2bf(g.w*(v.w-mean)*rstd + b.w);
  *reinterpret_cast<ushort4*>(out + (size_t)row*C_ + tid*4) = pk.u;
}

// ---------------- FFN2 reduction: out = out + p0 + p1 + bias ----------------
__global__ __launch_bounds__(256)
void k_add2(const bf16_t* __restrict__ p0, const bf16_t* __restrict__ p1,
            const float* __restrict__ bias, float* out){
  const int row = blockIdx.x, tid = threadIdx.x;
  float4 xr = reinterpret_cast<const float4*>(out + (size_t)row*C_)[tid];
  const ushort4 a = reinterpret_cast<const ushort4*>(p0 + (size_t)row*C_)[tid];
  const ushort4 b = reinterpret_cast<const ushort4*>(p1 + (size_t)row*C_)[tid];
  const float4 g = reinterpret_cast<const float4*>(bias)[tid];
  xr.x += bfraw2f(a.x) + bfraw2f(b.x) + g.x;
  xr.y += bfraw2f(a.y) + bfraw2f(b.y) + g.y;
  xr.z += bfraw2f(a.z) + bfraw2f(b.z) + g.z;
  xr.w += bfraw2f(a.w) + bfraw2f(b.w) + g.w;
  reinterpret_cast<float4*>(out + (size_t)row*C_)[tid] = xr;
}

// ---------------- GEMM A: 256x256, BK=64, 8 waves (2Mx4N), 8-phase, PERSISTENT ----------
// (r13 schedule: read spread {12,4,8,0}; loop-top vmcnt(6); prologue-during-epilogue)
// MODE 0: QKV split; MODE 2: bias+GELU->bf16; MODE 4: raw bf16 split-K partial.
template<int MODE>
__global__ __launch_bounds__(512, 1)
void k_gemm9(const bf16_t* __restrict__ A, const bf16_t* __restrict__ Bt,
             const float* __restrict__ bias, const float* resid,
             void* out0, void* out1, void* out2,
             int N, int ld, int klen, int gx, int tc)
{
  __shared__ __align__(16) bf16_t As[2][2][128*64];
  __shared__ __align__(16) bf16_t Bs[2][2][128*64];
  const int tid = threadIdx.x, lane = tid & 63, w = tid >> 6;
  const int wm = w >> 2, wn = w & 3;
  const int koff = blockIdx.z * klen;

  const int sswz = ((lane & 7) ^ ((lane >> 3) & 7)) * 8;
  const int srow = w * 8 + (lane >> 3);

  int row0, col0;
  const bf16_t *Agb, *Bgb;
  auto set_tile = [&](int tile){
    const int swz = (tile & 7) * (tc >> 3) + (tile >> 3);   // bijective, tc%8==0
    const int ct = swz % gx, rt = swz / gx;
    row0 = rt * 256; col0 = ct * 256;
    Agb = A  + (size_t)(row0 + srow) * ld + koff + sswz;
    Bgb = Bt + (size_t)(col0 + srow) * ld + koff + sswz;
  };

  auto stageA = [&](int tt, int hh){
    const bf16_t* src = Agb + (size_t)(hh * 128) * ld + tt * 64;
    bf16_t* dst = &As[tt & 1][hh][w * 512];
    glds16(src, dst);
    glds16(src + (size_t)64 * ld, dst + 4096);
  };
  auto stageB = [&](int tt, int hh){
    const bf16_t* src = Bgb + (size_t)(hh * 128) * ld + tt * 64;
    bf16_t* dst = &Bs[tt & 1][hh][w * 512];
    glds16(src, dst);
    glds16(src + (size_t)64 * ld, dst + 4096);
  };
  auto stage_prologue = [&](){
    stageA(0,0); stageA(0,1); stageB(0,0); stageB(0,1);
    stageB(1,0); stageB(1,1); stageA(1,0);
  };

  v8bf af[4][2], bfv[4][2];
  v4f acc[8][4];

  auto LDA = [&](int bb, int mh){
    const bf16_t* base = &As[bb][wm][0];
    #pragma unroll
    for (int m = 0; m < 4; ++m)
      #pragma unroll
      for (int kk = 0; kk < 2; ++kk) {
        const int r  = mh*64 + m*16 + (lane & 15);
        const int sl = (kk*4 + (lane >> 4)) ^ (lane & 7);
        af[m][kk] = *reinterpret_cast<const v8bf*>(base + r*64 + sl*8);
      }
  };
  auto LDB4 = [&](int bb, int nh){
    const bf16_t* base = &Bs[bb][wn >> 1][0];
    #pragma unroll
    for (int n = 0; n < 2; ++n)
      #pragma unroll
      for (int kk = 0; kk < 2; ++kk) {
        const int r  = (wn & 1)*64 + (nh*2+n)*16 + (lane & 15);
        const int sl = (kk*4 + (lane >> 4)) ^ (lane & 7);
        bfv[nh*2+n][kk] = *reinterpret_cast<const v8bf*>(base + r*64 + sl*8);
      }
  };

#define MFMA_Q(mh_, nh_) \
  __builtin_amdgcn_s_setprio(1); \
  _Pragma("unroll") \
  for (int kk = 0; kk < 2; ++kk) \
    _Pragma("unroll") \
    for (int m = 0; m < 4; ++m) \
      _Pragma("unroll") \
      for (int n = 0; n < 2; ++n) \
        acc[(mh_)*4+m][(nh_)*2+n] = __builtin_amdgcn_mfma_f32_16x16x32_bf16( \
            af[m][kk], bfv[(nh_)*2+n][kk], acc[(mh_)*4+m][(nh_)*2+n], 0,0,0); \
  __builtin_amdgcn_s_setprio(0);

#define BAR()   __builtin_amdgcn_s_barrier()
#define LGKM0() do { asm volatile("s_waitcnt lgkmcnt(0)" ::: "memory"); \
                     __builtin_amdgcn_sched_barrier(0); } while(0)

  const int NP = (klen >> 6) >> 1;
  int tile = blockIdx.x;
  set_tile(tile);
  stage_prologue();

  for (;;) {
    asm volatile("s_waitcnt vmcnt(6)" ::: "memory");   // drain this tile's K0 A+B only
    BAR();
    #pragma unroll
    for (int mf = 0; mf < 8; ++mf)
      #pragma unroll
      for (int nf = 0; nf < 4; ++nf)
        acc[mf][nf] = (v4f){0.f, 0.f, 0.f, 0.f};

    for (int j = 0; j < NP; ++j) {
      const int t2 = 2*j + 2, t3 = 2*j + 3;
      const bool more = (j + 1 < NP);
      // ---- ph1: 12 reads ----
      LDA(0, 0); LDB4(0, 0);
      stageA(2*j + 1, 1);
      BAR(); LGKM0(); MFMA_Q(0, 0); BAR();
      // ---- ph2: 4 reads ----
      LDB4(0, 1);
      if (more) stageB(t2, 0);
      BAR(); LGKM0(); MFMA_Q(0, 1); BAR();
      // ---- ph3: 8 reads ----
      LDA(0, 1);
      if (more) stageB(t2, 1);
      BAR(); LGKM0(); MFMA_Q(1, 0); BAR();
      // ---- ph4: 0 reads ----
      if (more) { stageA(t2, 0); asm volatile("s_waitcnt vmcnt(6)" ::: "memory"); }
      else      {                asm volatile("s_waitcnt vmcnt(0)" ::: "memory"); }
      BAR(); MFMA_Q(1, 1); BAR();
      // ---- ph5: 12 reads ----
      LDA(1, 0); LDB4(1, 0);
      if (more) stageA(t2, 1);
      BAR(); LGKM0(); MFMA_Q(0, 0); BAR();
      // ---- ph6: 4 reads ----
      LDB4(1, 1);
      if (more) stageB(t3, 0);
      BAR(); LGKM0(); MFMA_Q(0, 1); BAR();
      // ---- ph7: 8 reads ----
      LDA(1, 1);
      if (more) stageB(t3, 1);
      BAR(); LGKM0(); MFMA_Q(1, 0); BAR();
      // ---- ph8: 0 reads ----
      if (more) { stageA(t3, 0); asm volatile("s_waitcnt vmcnt(6)" ::: "memory"); }
      else      {                asm volatile("s_waitcnt vmcnt(0)" ::: "memory"); }
      BAR(); MFMA_Q(1, 1); BAR();
    }

    // issue next tile's prologue BEFORE the epilogue (HBM latency hides under it)
    const int erow0 = row0, ecol0 = col0;
    const int next = tile + (int)gridDim.x;
    const bool have_next = (next < tc);
    if (have_next) { set_tile(next); stage_prologue(); }

    #pragma unroll
    for (int mf = 0; mf < 8; ++mf) {
      const int rbase = erow0 + wm*128 + mf*16 + (lane>>4)*4;
      #pragma unroll
      for (int nf = 0; nf < 4; ++nf) {
        const int c = ecol0 + wn*64 + nf*16 + (lane&15);
        #pragma unroll
        for (int i = 0; i < 4; ++i) {
          const int rr = rbase + i;
          float v = acc[mf][nf][i];
          if constexpr(MODE==0){
            const int sec = c >> 10, cc = c & 1023;
            const int h = cc >> 6, d = cc & 63;
            const int b = rr >> 11, t = rr & 2047;
            if(sec==0)      ((bf16_t*)out0)[((size_t)(b*H_ + h)*T_ + t)*D_ + d] = f2bf(v * QSCALE);
            else if(sec==1) ((bf16_t*)out1)[((size_t)(b*H_ + h)*T_ + t)*D_ + d] = f2bf(v);
            else            ((bf16_t*)out2)[((size_t)(b*H_ + h)*D_ + d)*T_ + t] = f2bf(v);
          } else if constexpr(MODE==2){
            ((bf16_t*)out0)[(size_t)rr*N + c] = f2bf(gelu_fast(v + bias[c]));
          } else {  // MODE 4: raw bf16 partial
            bf16_t* dst = blockIdx.z ? (bf16_t*)out1 : (bf16_t*)out0;
            dst[(size_t)rr*N + c] = f2bf(v);
          }
        }
      }
    }
    if (!have_next) break;
    tile = next;
  }
#undef MFMA_Q
#undef BAR
#undef LGKM0
}

// ---------------- GEMM B: 256x128 tile, BK=64, 8 waves, 4-phase (proj only) ----
__global__ __launch_bounds__(512, 1)
void k_gemm8(const bf16_t* __restrict__ A, const bf16_t* __restrict__ Bt,
             const float* __restrict__ bias, const float* resid,
             float* out0, int N, int K, int gx)
{
  __shared__ __align__(16) bf16_t As[2][256*64];
  __shared__ __align__(16) bf16_t Bs[3][128*64];
  const int tid = threadIdx.x, lane = tid & 63, w = tid >> 6;
  const int wm = w >> 1, wn = w & 1;

  const int nwg = gx * 32;
  const int orig = blockIdx.y * gx + blockIdx.x;
  const int swz = (orig & 7) * (nwg >> 3) + (orig >> 3);
  const int ct = swz % gx, rt = swz / gx;
  const int row0 = rt * 256, col0 = ct * 128;

  const int sswz = ((lane & 7) ^ ((lane >> 3) & 7)) * 8;
  const int srow = w * 8 + (lane >> 3);
  const bf16_t* Agb = A  + (size_t)(row0 + srow) * K + sswz;
  const bf16_t* Bgb = Bt + (size_t)(col0 + srow) * K + sswz;

  auto stageA = [&](int tt){
    const bf16_t* src = Agb + tt * 64;
    bf16_t* dst = &As[tt & 1][w * 512];
    #pragma unroll
    for (int i = 0; i < 4; ++i)
      glds16(src + (size_t)(i*64) * K, dst + i*4096);
  };
  auto stageB = [&](int tt){
    const bf16_t* src = Bgb + tt * 64;
    bf16_t* dst = &Bs[tt % 3][w * 512];
    #pragma unroll
    for (int i = 0; i < 2; ++i)
      glds16(src + (size_t)(i*64) * K, dst + i*4096);
  };

  v8bf af[4][2], bfv[4][2];
  v4f acc[4][4] = {};

  auto LDA = [&](int ab){
    const bf16_t* base = &As[ab][0];
    #pragma unroll
    for (int m = 0; m < 4; ++m)
      #pragma unroll
      for (int kk = 0; kk < 2; ++kk) {
        const int r  = wm*64 + m*16 + (lane & 15);
        const int sl = (kk*4 + (lane >> 4)) ^ (lane & 7);
        af[m][kk] = *reinterpret_cast<const v8bf*>(base + r*64 + sl*8);
      }
  };
  auto LDB = [&](int bb, int nh){
    const bf16_t* base = &Bs[bb][0];
    #pragma unroll
    for (int n = 0; n < 2; ++n)
      #pragma unroll
      for (int kk = 0; kk < 2; ++kk) {
        const int r  = wn*64 + (nh*2+n)*16 + (lane & 15);
        const int sl = (kk*4 + (lane >> 4)) ^ (lane & 7);
        bfv[nh*2+n][kk] = *reinterpret_cast<const v8bf*>(base + r*64 + sl*8);
      }
  };

#define MFMA_Q(nh_) \
  __builtin_amdgcn_s_setprio(1); \
  _Pragma("unroll") \
  for (int kk = 0; kk < 2; ++kk) \
    _Pragma("unroll") \
    for (int m = 0; m < 4; ++m) \
      _Pragma("unroll") \
      for (int n = 0; n < 2; ++n) \
        acc[m][(nh_)*2+n] = __builtin_amdgcn_mfma_f32_16x16x32_bf16( \
            af[m][kk], bfv[(nh_)*2+n][kk], acc[m][(nh_)*2+n], 0,0,0); \
  __builtin_amdgcn_s_setprio(0);

#define BAR()   __builtin_amdgcn_s_barrier()
#define LGKM0() do { asm volatile("s_waitcnt lgkmcnt(0)" ::: "memory"); \
                     __builtin_amdgcn_sched_barrier(0); } while(0)
#define VM6()   asm volatile("s_waitcnt vmcnt(6)" ::: "memory")
#define VM0()   asm volatile("s_waitcnt vmcnt(0)" ::: "memory")

  const int NP = (K >> 6) >> 1;
  stageB(0); stageA(0); stageB(1); stageA(1);
  VM6();
  BAR();

  for (int j = 0; j < NP; ++j) {
    const int t0 = 2*j, t1 = 2*j + 1, t2 = 2*j + 2, t3 = 2*j + 3;
    const bool more = (j + 1 < NP);
    LDA(0); LDB(t0 % 3, 0);
    if (more) stageB(t2);
    BAR(); LGKM0(); MFMA_Q(0); BAR();
    LDB(t0 % 3, 1);
    if (more) { stageA(t2); VM6(); } else { VM0(); }
    BAR(); LGKM0(); MFMA_Q(1); BAR();
    LDA(1); LDB(t1 % 3, 0);
    if (more) stageB(t3);
    BAR(); LGKM0(); MFMA_Q(0); BAR();
    LDB(t1 % 3, 1);
    if (more) { stageA(t3); VM6(); } else { VM0(); }
    BAR(); LGKM0(); MFMA_Q(1); BAR();
  }
#undef MFMA_Q
#undef BAR
#undef LGKM0
#undef VM6
#undef VM0

  #pragma unroll
  for (int mf = 0; mf < 4; ++mf) {
    const int rbase = row0 + wm*64 + mf*16 + (lane>>4)*4;
    #pragma unroll
    for (int nf = 0; nf < 4; ++nf) {
      const int c = col0 + wn*64 + nf*16 + (lane&15);
      #pragma unroll
      for (int i = 0; i < 4; ++i) {
        const int rr = rbase + i;
        out0[(size_t)rr*N + c] = acc[mf][nf][i] + bias[c] + resid[(size_t)rr*N + c];
      }
    }
  }
}

// ---------------- causal flash attention, swapped-operand 32x32 (unchanged) ----------------
__global__ __launch_bounds__(256)
void k_attn(const bf16_t* __restrict__ Q, const bf16_t* __restrict__ Kg,
            const bf16_t* __restrict__ Vt, bf16_t* __restrict__ O)
{
  __shared__ __align__(16) bf16_t Ks [64][72];
  __shared__ __align__(16) bf16_t Vts[64][72];
  __shared__ __align__(16) bf16_t Os [128][72];
  const int bh = blockIdx.y;
  const int pair = blockIdx.x;
  const int tid = threadIdx.x, lane = tid & 63, w = tid >> 6;
  const int ql = lane & 31, hi = lane >> 5;
  const int srow = tid >> 2;
  const int scol = (tid & 3) * 16;
  const bf16_t* Kgp = Kg + ((size_t)bh*T_ + srow)*D_ + scol;
  const bf16_t* Vtp = Vt + ((size_t)bh*D_ + srow)*T_ + scol;
  const int b = bh >> 4, h = bh & 15;

  for(int half=0; half<2; ++half){
    const int qt = half ? pair : (15 - pair);
    const int qbase = qt*128 + w*32;
    const int q = qbase + ql;

    v8bf qf[4];
    {
      const bf16_t* Qb = Q + ((size_t)bh*T_ + q)*D_ + hi*8;
      #pragma unroll
      for(int ds=0; ds<4; ds++)
        qf[ds] = *reinterpret_cast<const v8bf*>(Qb + ds*16);
    }

    f32x16 accO[2] = {};
    float mrun = -1e30f, lrun = 0.0f;
    const int NT = (qt + 1) * 2;

    v8bf kr0 = *reinterpret_cast<const v8bf*>(Kgp);
    v8bf kr1 = *reinterpret_cast<const v8bf*>(Kgp + 8);
    v8bf vr0 = *reinterpret_cast<const v8bf*>(Vtp);
    v8bf vr1 = *reinterpret_cast<const v8bf*>(Vtp + 8);

    for(int t=0; t<NT; t++){
      const int kv0 = t*64;
      *reinterpret_cast<v8bf*>(&Ks [srow][scol  ]) = kr0;
      *reinterpret_cast<v8bf*>(&Ks [srow][scol+8]) = kr1;
      *reinterpret_cast<v8bf*>(&Vts[srow][scol  ]) = vr0;
      *reinterpret_cast<v8bf*>(&Vts[srow][scol+8]) = vr1;
      __syncthreads();
      if(t+1 < NT){
        const size_t kn = (size_t)(kv0 + 64);
        kr0 = *reinterpret_cast<const v8bf*>(Kgp + kn*D_);
        kr1 = *reinterpret_cast<const v8bf*>(Kgp + kn*D_ + 8);
        vr0 = *reinterpret_cast<const v8bf*>(Vtp + kn);
        vr1 = *reinterpret_cast<const v8bf*>(Vtp + kn + 8);
      }

      if(kv0 <= qbase + 31){
        f32x16 sT[2] = {};
        #pragma unroll
        for(int kvh=0; kvh<2; kvh++)
          #pragma unroll
          for(int ds=0; ds<4; ds++){
            v8bf kf = *reinterpret_cast<const v8bf*>(&Ks[kvh*32 + ql][ds*16 + hi*8]);
            sT[kvh] = __builtin_amdgcn_mfma_f32_32x32x16_bf16(kf, qf[ds], sT[kvh], 0,0,0);
          }

        if(kv0 + 63 > qbase){
          const int qrel = q - kv0 - hi*4;
          #pragma unroll
          for(int kvh=0; kvh<2; kvh++)
            #pragma unroll
            for(int r=0; r<16; r++){
              const int c = kvh*32 + (r&3) + 8*(r>>2);
              if(c > qrel) sT[kvh][r] = -1e30f;
            }
        }

        float pm = sT[0][0];
        #pragma unroll
        for(int r=1; r<16; r++) pm = fmaxf(pm, sT[0][r]);
        #pragma unroll
        for(int r=0; r<16; r++) pm = fmaxf(pm, sT[1][r]);
        pm = fmaxf(pm, __shfl_xor(pm, 32));

        if(__any(pm - mrun > 8.0f)){
          const float mnew = fmaxf(mrun, pm);
          const float corr = __builtin_amdgcn_exp2f(mrun - mnew);
          mrun = mnew;
          lrun *= corr;
          #pragma unroll
          for(int dh=0; dh<2; dh++)
            #pragma unroll
            for(int r=0; r<16; r++) accO[dh][r] *= corr;
        }

        float rs = 0.0f;
        #pragma unroll
        for(int kvh=0; kvh<2; kvh++)
          #pragma unroll
          for(int r=0; r<16; r++){
            float p = __builtin_amdgcn_exp2f(sT[kvh][r] - mrun);
            sT[kvh][r] = p;
            rs += p;
          }
        rs += __shfl_xor(rs, 32);
        lrun += rs;

        v8bf pfrag[4];
        #pragma unroll
        for(int s4=0; s4<4; s4++){
          const int kvh = s4>>1, bb = (s4&1)*8;
          uint32_t wa = cvt_pk_bf16(sT[kvh][bb+0], sT[kvh][bb+1]);
          uint32_t wb = cvt_pk_bf16(sT[kvh][bb+2], sT[kvh][bb+3]);
          uint32_t wc = cvt_pk_bf16(sT[kvh][bb+4], sT[kvh][bb+5]);
          uint32_t wd = cvt_pk_bf16(sT[kvh][bb+6], sT[kvh][bb+7]);
          uint32_t xwa = (uint32_t)__shfl_xor((int)wa, 32);
          uint32_t xwb = (uint32_t)__shfl_xor((int)wb, 32);
          uint32_t xwc = (uint32_t)__shfl_xor((int)wc, 32);
          uint32_t xwd = (uint32_t)__shfl_xor((int)wd, 32);
          union { uint32_t u[4]; v8bf v; } pk;
          pk.u[0] = hi ? xwc : wa;
          pk.u[1] = hi ? xwd : wb;
          pk.u[2] = hi ? wc  : xwa;
          pk.u[3] = hi ? wd  : xwb;
          pfrag[s4] = pk.v;
        }

        #pragma unroll
        for(int dh=0; dh<2; dh++)
          #pragma unroll
          for(int s4=0; s4<4; s4++){
            v8bf vf = *reinterpret_cast<const v8bf*>(&Vts[dh*32 + ql][s4*16 + hi*8]);
            accO[dh] = __builtin_amdgcn_mfma_f32_32x32x16_bf16(vf, pfrag[s4], accO[dh], 0,0,0);
          }
      }
      __syncthreads();
    }

    const float inv = 1.0f / lrun;
    #pragma unroll
    for(int dh=0; dh<2; dh++)
      #pragma unroll
      for(int rg=0; rg<4; rg++){
        uint32_t lo_ = cvt_pk_bf16(accO[dh][rg*4+0]*inv, accO[dh][rg*4+1]*inv);
        uint32_t hi_ = cvt_pk_bf16(accO[dh][rg*4+2]*inv, accO[dh][rg*4+3]*inv);
        uint2 w2; w2.x = lo_; w2.y = hi_;
        *reinterpret_cast<uint2*>(&Os[w*32 + ql][dh*32 + rg*8 + hi*4]) = w2;
      }
    __syncthreads();
    const int orow = tid >> 1, ocol = (tid & 1) * 32;
    bf16_t* Og = O + ((size_t)(b*T_ + qt*128 + orow))*C_ + h*64 + ocol;
    #pragma unroll
    for(int j=0;j<4;j++)
      *reinterpret_cast<v8bf*>(Og + j*8) = *reinterpret_cast<const v8bf*>(&Os[orow][ocol + j*8]);
    __syncthreads();
  }
}

// ---------------- launch ----------------
extern "C" void kernel_launch(void* const* d_in, const int* in_sizes, int n_in,
                              void* d_out, int out_size, void* d_ws, size_t ws_size,
                              hipStream_t stream) {
  const float* x      = (const float*)d_in[0];
  const float* w_qkv  = (const float*)d_in[1];
  const float* w_proj = (const float*)d_in[2];
  const float* b_proj = (const float*)d_in[3];
  const float* w1     = (const float*)d_in[4];
  const float* b1     = (const float*)d_in[5];
  const float* w2     = (const float*)d_in[6];
  const float* b2     = (const float*)d_in[7];
  const float* gamma1 = (const float*)d_in[8];
  const float* beta1  = (const float*)d_in[9];
  const float* gamma2 = (const float*)d_in[10];
  const float* beta2  = (const float*)d_in[11];

  char* ws = (char*)d_ws;
  bf16_t* wqkv_t  = (bf16_t*)(ws + 0);           // 3072x1024
  bf16_t* wproj_t = (bf16_t*)(ws + 6291456);     // 1024x1024
  bf16_t* w1_t    = (bf16_t*)(ws + 8388608);     // 4096x1024
  bf16_t* w2_t    = (bf16_t*)(ws + 16777216);    // 1024x4096
  bf16_t* qb      = (bf16_t*)(ws + 25165824);    // [B,H,T,D]
  bf16_t* kb      = (bf16_t*)(ws + 41943040);    // [B,H,T,D]
  bf16_t* vtb     = (bf16_t*)(ws + 58720256);    // [B,H,D,T]
  bf16_t* obuf    = (bf16_t*)(ws + 75497472);    // [B,T,C]; FFN2 partial p0
  bf16_t* hb      = (bf16_t*)(ws + 92274688);    // [M,C]; FFN2 partial p1
  bf16_t* gb      = (bf16_t*)(ws + 25165824);    // [M,4C] bf16 (reuses q..o)
  float*  x2      = (float*)d_out;               // x after attn residual (aliases out)

  // transposes + LN1 in one dispatch
  k_prep<<<20480, 256, 0, stream>>>(w_qkv, wqkv_t, w_proj, wproj_t,
                                    w1, w1_t, w2, w2_t,
                                    x, gamma1, beta1, hb);

  // QKV: persistent 256x256 8-phase, tc=384 tiles over 256 blocks
  k_gemm9<0><<<dim3(256, 1, 1), 512, 0, stream>>>(hb, wqkv_t, nullptr, nullptr,
                                                  qb, kb, vtb, 3072, 1024, 1024, 12, 384);
  k_attn<<<dim3(8, B_*H_), 256, 0, stream>>>(qb, kb, vtb, obuf);

  // proj: 256x128 4-phase, 256 blocks
  k_gemm8<<<dim3(8, 32), 512, 0, stream>>>(obuf, wproj_t, b_proj, x,
                                           x2, 1024, 1024, 8);
  k_layernorm<<<M_, 256, 0, stream>>>(x2, gamma2, beta2, hb);

  // FFN1: persistent 256x256 8-phase, tc=512 tiles over 256 blocks (2 each)
  k_gemm9<2><<<dim3(256, 1, 1), 512, 0, stream>>>(hb, w1_t, b1, nullptr,
                                                  gb, nullptr, nullptr, 4096, 1024, 1024, 16, 512);
  // FFN2: split-K=2 on 256x256 8-phase, 128 blocks x 2 z; partials p0=obuf, p1=hb
  k_gemm9<4><<<dim3(128, 1, 2), 512, 0, stream>>>(gb, w2_t, nullptr, nullptr,
                                                  obuf, hb, nullptr, 1024, 4096, 2048, 4, 128);
  k_add2<<<M_, 256, 0, stream>>>(obuf, hb, b2, x2);
}